// Round 5
// baseline (1837.764 us; speedup 1.0000x reference)
//
#include <hip/hip_runtime.h>

// Forest-Ruth integrator via bf16x3-split MFMA (32x32x16), B=32768, D=512, K=64.
// ROUND 5: 16-wave blocks (1024 threads), 32 rows/block, grid 1024, 1 block/CU.
// Rationale: rounds 0-4 showed all pipes <12-25% busy => latency-bound at
// 2 waves/SIMD (255-reg waves). This version spreads the same block work over
// 16 waves so per-lane register need drops to ~112 (<128) => 4 waves/SIMD:
//   frag[8] (32 regs) time-shared U<->W (r4-proven; reload from L2 per substep)
//   vst/xst 16+16 (one 32x32 C/D tile per wave), single 16-reg accumulator
//   (3 bf16x3 passes chained into one acc; rounding-order change only)
//   f in LDS. __launch_bounds__(1024,4) pins the 128-reg budget.
// GEMM1 split: wave w -> (nt1 = w&1 h-col-tile, ks8 = w>>1 d-range of 64).
// GEMM2 split: wave w -> christ col-tile 32w..32w+32. State cols = 32w+(lane&31).
// HB now sums 8 partials/cell via atomics (was 4+4) - order within existing
// atomic nondeterminism. Kept: VF/GF slot swizzle, HB read-then-zero.

#define NTH 1024

// LDS word-offsets (4B words)
#define VF0 0          // v-frag plane j0..3 : [32 kstep][64 slot][4 words], slot swizzled
#define VF1 8192       // v-frag plane j4..7
#define GF0 16384      // g-frag plane j0..3 : [4 kstep][64 slot][4 words], slot swizzled
#define GF1 17408      // g-frag plane j4..7
#define HB  18432      // h buffer fp32 [32][68]
#define FB  20608      // f buffer fp32 [32][516]
#define LDS_WORDS 37120
#define LDS_BYTES (LDS_WORDS*4)   // 148480 B

typedef __attribute__((ext_vector_type(8))) short short8;
typedef __attribute__((ext_vector_type(16))) float float16;

__device__ __forceinline__ float wrap_torus(float y) {
    const float PI_F  = 3.14159265358979323846f;
    const float TPI_F = 6.28318530717958647692f;
    float t = y + PI_F;
    if (t >= TPI_F) t -= TPI_F;
    else if (t < 0.0f) t += TPI_F;
    return t - PI_F;
}

__device__ __forceinline__ void split2(float v, unsigned short& hi, unsigned short& lo) {
    unsigned u = __float_as_uint(v);
    unsigned h = (u + 0x7fffu + ((u >> 16) & 1u)) >> 16;    // RNE to bf16
    hi = (unsigned short)h;
    float hf = __uint_as_float(h << 16);
    float r = v - hf;                                        // exact
    unsigned u2 = __float_as_uint(r);
    unsigned l = (u2 + 0x7fffu + ((u2 >> 16) & 1u)) >> 16;
    lo = (unsigned short)l;
}

__device__ __forceinline__ unsigned pack_split(float v) {
    unsigned short hi, lo;
    split2(v, hi, lo);
    return (((unsigned)hi) << 16) | (unsigned)lo;
}

__device__ __forceinline__ void unpack_frag(uint4 l4, uint4 h4, short8& fhi, short8& flo) {
    fhi[0]=(short)(l4.x>>16); flo[0]=(short)(l4.x&0xffffu);
    fhi[1]=(short)(l4.y>>16); flo[1]=(short)(l4.y&0xffffu);
    fhi[2]=(short)(l4.z>>16); flo[2]=(short)(l4.z&0xffffu);
    fhi[3]=(short)(l4.w>>16); flo[3]=(short)(l4.w&0xffffu);
    fhi[4]=(short)(h4.x>>16); flo[4]=(short)(h4.x&0xffffu);
    fhi[5]=(short)(h4.y>>16); flo[5]=(short)(h4.y&0xffffu);
    fhi[6]=(short)(h4.z>>16); flo[6]=(short)(h4.z&0xffffu);
    fhi[7]=(short)(h4.w>>16); flo[7]=(short)(h4.w&0xffffu);
}

// Bijective slot swizzle (6-bit): fold bit5 into quad-bit1 and kst low bits
// into quad-bits 0/1. Store uses swz(m+32*lb, kst); read uses swz(lane, kst).
__device__ __forceinline__ int swz(int s, int kst) {
    return s ^ ((s >> 5) << 1) ^ (kst & 3);
}

__device__ __forceinline__ void vf_store(unsigned int* ldsu, int m, int d, unsigned p) {
    int kst = d >> 4, lb = (d >> 3) & 1, j = d & 7;
    int slot = swz(m + 32 * lb, kst);
    ldsu[((j >> 2) ? VF1 : VF0) + (kst * 64 + slot) * 4 + (j & 3)] = p;
}

// ---- prep: split U, W to bf16 hi/lo in MFMA B-frag swizzled layout in d_ws.
// U frag (nt1,ks8,c): B[k][n]: n = 32*nt1+(lane&31), d = 64*ks8+16*c+8*(lane>>5)+j
// W frag (ct,kk):     B[k][n]: n = 32*ct +(lane&31), k = 16*kk+8*(lane>>5)+j
__global__ void fr_prep(const float* __restrict__ Um, const float* __restrict__ Wm,
                        unsigned short* __restrict__ usw, unsigned short* __restrict__ wsw) {
    int tid = blockIdx.x * 256 + threadIdx.x;   // 8192 total
    int lane = tid & 63;
    if (tid < 4096) {
        int c   = (tid >> 6) & 3;
        int ks8 = (tid >> 8) & 7;
        int nt1 = (tid >> 11) & 1;
        int fbase = (((nt1 * 8 + ks8) * 4 + c) * 2) * 512;   // ushort units
        #pragma unroll
        for (int j = 0; j < 8; ++j) {
            int d = 64 * ks8 + 16 * c + 8 * (lane >> 5) + j;
            int n = 32 * nt1 + (lane & 31);
            unsigned short hi, lo;
            split2(Um[d * 64 + n], hi, lo);
            usw[fbase + lane * 8 + j] = hi;
            usw[fbase + 512 + lane * 8 + j] = lo;
        }
    } else {
        int id = tid - 4096;
        lane = id & 63;
        int kk = (id >> 6) & 3;
        int ct = (id >> 8) & 15;
        int fbase = ((ct * 4 + kk) * 2) * 512;
        #pragma unroll
        for (int j = 0; j < 8; ++j) {
            int k = 16 * kk + 8 * (lane >> 5) + j;
            int n = 32 * ct + (lane & 31);
            unsigned short hi, lo;
            split2(Wm[k * 512 + n], hi, lo);
            wsw[fbase + lane * 8 + j] = hi;
            wsw[fbase + 512 + lane * 8 + j] = lo;
        }
    }
}

__global__ __launch_bounds__(NTH, 4) void fr_mfma(
    const float* __restrict__ xin, const float* __restrict__ vin,
    const float* __restrict__ fin,
    const short8* __restrict__ usw, const short8* __restrict__ wsw,
    float* __restrict__ xout, float* __restrict__ vout)
{
    extern __shared__ float lds[];
    unsigned int* ldsu = (unsigned int*)lds;

    const int t = threadIdx.x;
    const int lane = t & 63;
    const int w = __builtin_amdgcn_readfirstlane(t >> 6);    // 0..15
    const int nt1 = w & 1;       // GEMM1 h-col tile
    const int ks8 = w >> 1;      // GEMM1 k-split (d range 64*ks8..+64)
    const int rhalf = lane >> 5;
    const int R0 = (int)blockIdx.x * 32;
    const int cg = w * 32 + (lane & 31);   // this thread's state/christ column
    const int lslot = lane ^ (rhalf << 1); // swz(lane, kst) = lslot ^ (kst&3)

    const double theta = 1.0 / (2.0 - 1.2599210498948732);
    const float c1dt = (float)(theta * 0.5 * 0.01);
    const float c2dt = (float)((1.0 - theta) * 0.5 * 0.01);
    const float d1dt = (float)(theta * 0.01);
    const float d2dt = (float)((1.0 - 2.0 * theta) * 0.01);

    // ---- ONE time-shared operand array (32 regs): U during GEMM1, W during
    //      GEMM2. frag[2c]/frag[2c+1] = Uhi/Ulo(c); frag[2kk]/frag[2kk+1] =
    //      Whi/Wlo(kk). Reloaded from L2-resident d_ws each substep.
    short8 frag[8];
    uintptr_t uop = (uintptr_t)usw;
    uintptr_t wop = (uintptr_t)wsw;
    const int ub8 = (nt1 * 8 + ks8) * 8;   // U frag base (short8 units of 64)
    const int wb8 = w * 8;                 // W frag base
    {
        const short8* up = (const short8*)uop;
        #pragma unroll
        for (int i = 0; i < 8; ++i)
            frag[i] = up[(ub8 + i) * 64 + lane];
    }

    // ---- state registers in C/D layout: col = cg, row = (r&3)+8*(r>>2)+4*rhalf
    float vst[16], xst[16];
    #pragma unroll
    for (int r = 0; r < 16; ++r) {
        int m = (r & 3) + 8 * (r >> 2) + 4 * rhalf;
        size_t idx = (size_t)(R0 + m) * 512 + cg;
        vst[r] = vin[idx];
        xst[r] = xin[idx];
    }

    // ---- stage f into LDS [32][516]
    {
        #pragma unroll
        for (int it = 0; it < 4; ++it) {
            int flat = it * 4096 + t * 4;
            float4 val = *(const float4*)(fin + (size_t)R0 * 512 + flat);
            int row = flat >> 9, col = flat & 511;
            *(float4*)(lds + FB + row * 516 + col) = val;
        }
    }

    // ---- x1 = wrap(x + c1dt*v); write v0 splits to vfrag
    #pragma unroll
    for (int r = 0; r < 16; ++r) {
        xst[r] = wrap_torus(xst[r] + c1dt * vst[r]);
        int m = (r & 3) + 8 * (r >> 2) + 4 * rhalf;
        vf_store(ldsu, m, cg, pack_split(vst[r]));
    }
    // zero hbuf (once; thereafter g-phase read-then-zero keeps it clean)
    for (int i = t; i < 32 * 68; i += NTH) lds[HB + i] = 0.0f;

    #pragma unroll 1
    for (int sub = 0; sub < 12; ++sub) {
        const int idx3 = sub - (sub / 3) * 3;
        const float ddt = (idx3 == 1) ? d2dt : d1dt;
        const float xc  = (idx3 == 2) ? c1dt : c2dt;
        const bool dbl  = (idx3 == 2) && (sub != 11);

        __syncthreads();   // B0: vfrag writes complete

        // ---- GEMM1: h-tile(nt1), d in [64*ks8, +64), 3-pass bf16x3 into ONE acc
        float16 acc;
        #pragma unroll
        for (int i = 0; i < 16; ++i) acc[i] = 0.0f;
        #pragma unroll
        for (int c = 0; c < 4; ++c) {
            int kst = ks8 * 4 + c;
            int slot = lslot ^ (kst & 3);
            uint4 pl = *(const uint4*)&ldsu[VF0 + (kst * 64 + slot) * 4];
            uint4 ph = *(const uint4*)&ldsu[VF1 + (kst * 64 + slot) * 4];
            short8 Ahi, Alo;
            unpack_frag(pl, ph, Ahi, Alo);
            acc = __builtin_amdgcn_mfma_f32_32x32x16_bf16(Ahi, frag[2 * c],     acc, 0, 0, 0);
            acc = __builtin_amdgcn_mfma_f32_32x32x16_bf16(Alo, frag[2 * c],     acc, 0, 0, 0);
            acc = __builtin_amdgcn_mfma_f32_32x32x16_bf16(Ahi, frag[2 * c + 1], acc, 0, 0, 0);
        }

        // ---- overwrite frag with W for this substep's GEMM2 (L2-resident;
        //      latency hidden under atomics + B1 + g-phase + B2)
        asm volatile("" : "+s"(wop));
        {
            const short8* wp = (const short8*)wop;
            #pragma unroll
            for (int i = 0; i < 8; ++i)
                frag[i] = wp[(wb8 + i) * 64 + lane];
        }

        // ---- accumulate partial h (8 contributions per cell across ks8)
        {
            int kcol = nt1 * 32 + (lane & 31);
            #pragma unroll
            for (int r = 0; r < 16; ++r) {
                int m = (r & 3) + 8 * (r >> 2) + 4 * rhalf;
                atomicAdd(&lds[HB + m * 68 + kcol], acc[r]);
            }
        }
        __syncthreads();   // B1: h complete

        // ---- g = h*h (2 cells/thread), split, write g-frags; zero h cells
        {
            int grow = t >> 5;
            int k2 = (t & 31) * 2;
            float2 h2 = *(const float2*)&lds[HB + grow * 68 + k2];
            float2 z2; z2.x = 0.0f; z2.y = 0.0f;
            *(float2*)&lds[HB + grow * 68 + k2] = z2;   // read-then-zero
            uint2 gp;
            gp.x = pack_split(h2.x * h2.x);
            gp.y = pack_split(h2.y * h2.y);
            int kst2 = k2 >> 4, lb2 = (k2 >> 3) & 1, jb = k2 & 7;
            int slot2 = swz(grow + 32 * lb2, kst2);
            *(uint2*)&ldsu[((jb >> 2) ? GF1 : GF0) + (kst2 * 64 + slot2) * 4 + (jb & 3)] = gp;
        }
        __syncthreads();   // B2: g-frags ready (also orders HB zero before next atomics)

        // ---- GEMM2: christ col-tile ct=w over K=64, 3-pass into ONE acc
        #pragma unroll
        for (int i = 0; i < 16; ++i) acc[i] = 0.0f;
        #pragma unroll
        for (int kk = 0; kk < 4; ++kk) {
            int slot = lslot ^ kk;
            uint4 pl = *(const uint4*)&ldsu[GF0 + (kk * 64 + slot) * 4];
            uint4 ph = *(const uint4*)&ldsu[GF1 + (kk * 64 + slot) * 4];
            short8 Ahi, Alo;
            unpack_frag(pl, ph, Ahi, Alo);
            acc = __builtin_amdgcn_mfma_f32_32x32x16_bf16(Ahi, frag[2 * kk],     acc, 0, 0, 0);
            acc = __builtin_amdgcn_mfma_f32_32x32x16_bf16(Alo, frag[2 * kk],     acc, 0, 0, 0);
            acc = __builtin_amdgcn_mfma_f32_32x32x16_bf16(Ahi, frag[2 * kk + 1], acc, 0, 0, 0);
        }

        // ---- refill frag with U for next substep's GEMM1 (hidden under
        //      epilogue VALU + vf_stores + B0 wait)
        if (sub != 11) {
            asm volatile("" : "+s"(uop));
            const short8* up = (const short8*)uop;
            #pragma unroll
            for (int i = 0; i < 8; ++i)
                frag[i] = up[(ub8 + i) * 64 + lane];
        }

        // ---- epilogue: v += ddt*(f - christ); x = wrap(x + xc*v) (+ fused c1);
        //      write new v splits for next substep
        #pragma unroll
        for (int r = 0; r < 16; ++r) {
            int m = (r & 3) + 8 * (r >> 2) + 4 * rhalf;
            float fv = lds[FB + m * 516 + cg];
            float vn = vst[r] + ddt * (fv - acc[r]);
            vst[r] = vn;
            float xn = wrap_torus(xst[r] + xc * vn);
            if (dbl) xn = wrap_torus(xn + c1dt * vn);
            xst[r] = xn;
            if (sub != 11) vf_store(ldsu, m, cg, pack_split(vn));
        }
    }

    // ---- store outputs
    #pragma unroll
    for (int r = 0; r < 16; ++r) {
        int m = (r & 3) + 8 * (r >> 2) + 4 * rhalf;
        size_t idx = (size_t)(R0 + m) * 512 + cg;
        xout[idx] = xst[r];
        vout[idx] = vst[r];
    }
}

extern "C" void kernel_launch(void* const* d_in, const int* in_sizes, int n_in,
                              void* d_out, int out_size, void* d_ws, size_t ws_size,
                              hipStream_t stream) {
    const float* x = (const float*)d_in[0];
    const float* v = (const float*)d_in[1];
    const float* f = (const float*)d_in[2];
    const float* U = (const float*)d_in[3];
    const float* W = (const float*)d_in[4];

    float* xout = (float*)d_out;
    float* vout = xout + (size_t)32768 * 512;

    unsigned short* usw = (unsigned short*)d_ws;               // 128 KiB
    unsigned short* wsw = usw + 65536;                          // 128 KiB

    fr_prep<<<32, 256, 0, stream>>>(U, W, usw, wsw);

    hipFuncSetAttribute(reinterpret_cast<const void*>(fr_mfma),
                        hipFuncAttributeMaxDynamicSharedMemorySize, LDS_BYTES);
    fr_mfma<<<1024, NTH, LDS_BYTES, stream>>>(
        x, v, f, (const short8*)usw, (const short8*)wsw, xout, vout);
}

// Round 6
// 1224.296 us; speedup vs baseline: 1.5011x; 1.5011x over previous
//
#include <hip/hip_runtime.h>

// Forest-Ruth integrator via bf16x3-split MFMA (32x32x16), B=32768, D=512, K=64.
// Block = 32 rows, 512 threads (8 waves), grid 1024. 1 block/CU (LDS-bound).
// ROUND 6: built on the round-4 structure (time-shared frag[16], clean regs,
// FETCH 183MB) with the g-phase ELIMINATED:
//   * GEMM2's A-fragments are built on-the-fly from HB: lane reads
//     h[lane&31][16kk+8(lane>>5)+j] (8 floats, 2xb128; stride 68 words => 17
//     words/quad, coprime => conflict-free), squares, split2s in-register.
//     Bit-identical to the old GF path (same post-B1 fp32 h, same split).
//   * B2 and the GF buffers are deleted: 2 block barriers/substep (24
//     intervals/block vs 36). Round-5 evidence: occupancy doesn't help (48%
//     occ, no gain) => the stall is the barrier-interval convoy; cut intervals.
//   * HB double-buffered (GF's freed 8.5KB): zero HB[next] in the B1->B0
//     window (ordered vs readers by B0 of this sub, vs next atomics by B0 of
//     next sub).
// Kept from round 4: U/W frag time-share (spill-proof), VF slot swizzle,
// W-reload after GEMM1, U-refill before epilogue. Numerics identical.

#define NTH 512

// LDS word-offsets (4B words)
#define VF0 0          // v-frag plane j0..3 : [32 kstep][64 slot][4 words], slot swizzled
#define VF1 8192       // v-frag plane j4..7
#define HB0W 16384     // h buffer fp32 [2][32][68] (double-buffered)
#define HBSZ 2176
#define FB  20736      // f buffer fp32 [32][516]
#define LDS_WORDS 37248
#define LDS_BYTES (LDS_WORDS*4)   // 148992 B

typedef __attribute__((ext_vector_type(8))) short short8;
typedef __attribute__((ext_vector_type(16))) float float16;

__device__ __forceinline__ float wrap_torus(float y) {
    const float PI_F  = 3.14159265358979323846f;
    const float TPI_F = 6.28318530717958647692f;
    float t = y + PI_F;
    if (t >= TPI_F) t -= TPI_F;
    else if (t < 0.0f) t += TPI_F;
    return t - PI_F;
}

__device__ __forceinline__ void split2(float v, unsigned short& hi, unsigned short& lo) {
    unsigned u = __float_as_uint(v);
    unsigned h = (u + 0x7fffu + ((u >> 16) & 1u)) >> 16;    // RNE to bf16
    hi = (unsigned short)h;
    float hf = __uint_as_float(h << 16);
    float r = v - hf;                                        // exact
    unsigned u2 = __float_as_uint(r);
    unsigned l = (u2 + 0x7fffu + ((u2 >> 16) & 1u)) >> 16;
    lo = (unsigned short)l;
}

__device__ __forceinline__ unsigned pack_split(float v) {
    unsigned short hi, lo;
    split2(v, hi, lo);
    return (((unsigned)hi) << 16) | (unsigned)lo;
}

__device__ __forceinline__ void unpack_frag(uint4 l4, uint4 h4, short8& fhi, short8& flo) {
    fhi[0]=(short)(l4.x>>16); flo[0]=(short)(l4.x&0xffffu);
    fhi[1]=(short)(l4.y>>16); flo[1]=(short)(l4.y&0xffffu);
    fhi[2]=(short)(l4.z>>16); flo[2]=(short)(l4.z&0xffffu);
    fhi[3]=(short)(l4.w>>16); flo[3]=(short)(l4.w&0xffffu);
    fhi[4]=(short)(h4.x>>16); flo[4]=(short)(h4.x&0xffffu);
    fhi[5]=(short)(h4.y>>16); flo[5]=(short)(h4.y&0xffffu);
    fhi[6]=(short)(h4.z>>16); flo[6]=(short)(h4.z&0xffffu);
    fhi[7]=(short)(h4.w>>16); flo[7]=(short)(h4.w&0xffffu);
}

// Square + split a pair of h values into frag lanes
__device__ __forceinline__ void gsplit(float h, short8& fhi, short8& flo, int j) {
    unsigned short hi, lo;
    split2(h * h, hi, lo);
    fhi[j] = (short)hi;
    flo[j] = (short)lo;
}

// Bijective slot swizzle (6-bit): fold bit5 into quad-bit1 and kst low bits
// into quad-bits 0/1. Store uses swz(m+32*lb, kst); read uses swz(lane, kst).
__device__ __forceinline__ int swz(int s, int kst) {
    return s ^ ((s >> 5) << 1) ^ (kst & 3);
}

__device__ __forceinline__ void vf_store(unsigned int* ldsu, int m, int d, unsigned p) {
    int kst = d >> 4, lb = (d >> 3) & 1, j = d & 7;
    int slot = swz(m + 32 * lb, kst);
    ldsu[((j >> 2) ? VF1 : VF0) + (kst * 64 + slot) * 4 + (j & 3)] = p;
}

// ---- prep: split U, W to bf16 hi/lo in MFMA B-frag swizzled layout in d_ws.
// U frag (nt1,ks4,c): B[k][n]: n = 32*nt1 + (lane&31), d = 128*ks4+16*c+8*(lane>>5)+j
// W frag (nt,kk):     B[k][n]: n = 32*nt  + (lane&31), k = 16*kk+8*(lane>>5)+j
__global__ void fr_prep(const float* __restrict__ Um, const float* __restrict__ Wm,
                        unsigned short* __restrict__ usw, unsigned short* __restrict__ wsw) {
    int tid = blockIdx.x * 256 + threadIdx.x;   // 8192 total
    int lane = tid & 63;
    if (tid < 4096) {
        int c   = (tid >> 6) & 7;
        int ks4 = (tid >> 9) & 3;
        int nt1 = (tid >> 11) & 1;
        int fbase = (((nt1 * 4 + ks4) * 8 + c) * 2) * 512;   // ushort units
        #pragma unroll
        for (int j = 0; j < 8; ++j) {
            int d = 128 * ks4 + 16 * c + 8 * (lane >> 5) + j;
            int n = 32 * nt1 + (lane & 31);
            unsigned short hi, lo;
            split2(Um[d * 64 + n], hi, lo);
            usw[fbase + lane * 8 + j] = hi;
            usw[fbase + 512 + lane * 8 + j] = lo;
        }
    } else {
        int id = tid - 4096;
        lane = id & 63;
        int kk = (id >> 6) & 3;
        int nt = (id >> 8) & 15;
        int fbase = ((nt * 4 + kk) * 2) * 512;
        #pragma unroll
        for (int j = 0; j < 8; ++j) {
            int k = 16 * kk + 8 * (lane >> 5) + j;
            int n = 32 * nt + (lane & 31);
            unsigned short hi, lo;
            split2(Wm[k * 512 + n], hi, lo);
            wsw[fbase + lane * 8 + j] = hi;
            wsw[fbase + 512 + lane * 8 + j] = lo;
        }
    }
}

__global__ __launch_bounds__(NTH, 2) void fr_mfma(
    const float* __restrict__ xin, const float* __restrict__ vin,
    const float* __restrict__ fin,
    const short8* __restrict__ usw, const short8* __restrict__ wsw,
    float* __restrict__ xout, float* __restrict__ vout)
{
    extern __shared__ float lds[];
    unsigned int* ldsu = (unsigned int*)lds;

    const int t = threadIdx.x;
    const int lane = t & 63;
    const int w = __builtin_amdgcn_readfirstlane(t >> 6);    // 0..7
    const int nt1 = w & 1;       // GEMM1 h-col tile
    const int ks4 = w >> 1;      // GEMM1 k-split (d range 128*ks4..+128)
    const int rhalf = lane >> 5;
    const int hrow = lane & 31;  // A-frag row for GEMM2 on-the-fly build
    const int R0 = (int)blockIdx.x * 32;

    const double theta = 1.0 / (2.0 - 1.2599210498948732);
    const float c1dt = (float)(theta * 0.5 * 0.01);
    const float c2dt = (float)((1.0 - theta) * 0.5 * 0.01);
    const float d1dt = (float)(theta * 0.01);
    const float d2dt = (float)((1.0 - 2.0 * theta) * 0.01);

    // ---- ONE time-shared operand array: holds U-frags during GEMM1,
    //      W-frags during GEMM2 (round-4 proven spill-free design).
    short8 frag[16];
    uintptr_t uop = (uintptr_t)usw;
    uintptr_t wop = (uintptr_t)wsw;
    const int ub = (nt1 * 4 + ks4) * 16;   // U frag plane base (short8 units of 64)
    const int wb = w * 16;                 // W frag plane base
    {
        const short8* up = (const short8*)uop;
        #pragma unroll
        for (int i = 0; i < 16; ++i)
            frag[i] = up[(ub + i) * 64 + lane];
    }

    // ---- state registers in C/D layout: col = 32*(2w+nt)+(lane&31),
    //      row = (r&3)+8*(r>>2)+4*rhalf
    float vst[2][16], xst[2][16];
    int cg[2];
    cg[0] = (w * 2 + 0) * 32 + (lane & 31);
    cg[1] = (w * 2 + 1) * 32 + (lane & 31);
    #pragma unroll
    for (int nt = 0; nt < 2; ++nt) {
        #pragma unroll
        for (int r = 0; r < 16; ++r) {
            int rrow = (r & 3) + 8 * (r >> 2) + 4 * rhalf;
            size_t idx = (size_t)(R0 + rrow) * 512 + cg[nt];
            vst[nt][r] = vin[idx];
            xst[nt][r] = xin[idx];
        }
    }

    // ---- stage f into LDS [32][516]
    {
        #pragma unroll
        for (int it = 0; it < 8; ++it) {
            int flat = it * 2048 + t * 4;
            float4 val = *(const float4*)(fin + (size_t)R0 * 512 + flat);
            int row = flat >> 9, col = flat & 511;
            *(float4*)(lds + FB + row * 516 + col) = val;
        }
    }

    // ---- x1 = wrap(x + c1dt*v)
    #pragma unroll
    for (int nt = 0; nt < 2; ++nt)
        #pragma unroll
        for (int r = 0; r < 16; ++r)
            xst[nt][r] = wrap_torus(xst[nt][r] + c1dt * vst[nt][r]);

    // ---- write v0 splits to vfrag; zero BOTH h buffers
    #pragma unroll
    for (int nt = 0; nt < 2; ++nt) {
        #pragma unroll
        for (int r = 0; r < 16; ++r) {
            int m = (r & 3) + 8 * (r >> 2) + 4 * rhalf;
            vf_store(ldsu, m, cg[nt], pack_split(vst[nt][r]));
        }
    }
    for (int i = t; i < 2 * HBSZ; i += NTH) lds[HB0W + i] = 0.0f;

    #pragma unroll 1
    for (int sub = 0; sub < 12; ++sub) {
        const int idx3 = sub - (sub / 3) * 3;
        const float ddt = (idx3 == 1) ? d2dt : d1dt;
        const float xc  = (idx3 == 2) ? c1dt : c2dt;
        const bool dbl  = (idx3 == 2) && (sub != 11);
        const int hbc = HB0W + (sub & 1) * HBSZ;          // current h buffer
        const int hbn = HB0W + ((sub + 1) & 1) * HBSZ;    // next h buffer

        __syncthreads();   // B0: vfrag writes + HB[cur] zero complete

        // ---- GEMM1: h-tile(nt1), d in [128*ks4, +128), 3-pass bf16x3
        //      (frag holds U: hi at frag[2c], lo at frag[2c+1])
        float16 acc0, acc1;
        #pragma unroll
        for (int i = 0; i < 16; ++i) { acc0[i] = 0.0f; acc1[i] = 0.0f; }
        #pragma unroll
        for (int c = 0; c < 8; ++c) {
            int kst = ks4 * 8 + c;
            int slot = swz(lane, kst);
            uint4 pl = *(const uint4*)&ldsu[VF0 + (kst * 64 + slot) * 4];
            uint4 ph = *(const uint4*)&ldsu[VF1 + (kst * 64 + slot) * 4];
            short8 Ahi, Alo;
            unpack_frag(pl, ph, Ahi, Alo);
            acc0 = __builtin_amdgcn_mfma_f32_32x32x16_bf16(Ahi, frag[2 * c],     acc0, 0, 0, 0);
            acc1 = __builtin_amdgcn_mfma_f32_32x32x16_bf16(Alo, frag[2 * c],     acc1, 0, 0, 0);
            acc1 = __builtin_amdgcn_mfma_f32_32x32x16_bf16(Ahi, frag[2 * c + 1], acc1, 0, 0, 0);
        }

        // ---- overwrite frag with W for this substep's GEMM2 (L2-resident;
        //      latency hidden under atomics + B1)
        asm volatile("" : "+s"(wop));
        {
            const short8* wp = (const short8*)wop;
            #pragma unroll
            for (int i = 0; i < 16; ++i)
                frag[i] = wp[(wb + i) * 64 + lane];
        }

        // ---- accumulate partial h into HB[cur]
        {
            int kcol = nt1 * 32 + (lane & 31);
            #pragma unroll
            for (int r = 0; r < 16; ++r) {
                int m = (r & 3) + 8 * (r >> 2) + 4 * rhalf;
                atomicAdd(&lds[hbc + m * 68 + kcol], acc0[r] + acc1[r]);
            }
        }
        __syncthreads();   // B1: h complete

        // ---- GEMM2: christ tiles 2w, 2w+1 over K=64. A-frags built on the
        //      fly from HB[cur]: lane reads h[hrow][16kk+8rhalf + 0..7]
        //      (stride 68 => conflict-free b128), squares + splits in-reg.
        //      Bit-identical to the old GF path.
        float16 cA, cB;
        #pragma unroll
        for (int i = 0; i < 16; ++i) { cA[i] = 0.0f; cB[i] = 0.0f; }
        #pragma unroll
        for (int kk = 0; kk < 4; ++kk) {
            int ha = hbc + hrow * 68 + 16 * kk + 8 * rhalf;
            float4 hA = *(const float4*)&lds[ha];
            float4 hB = *(const float4*)&lds[ha + 4];
            short8 Ahi, Alo;
            gsplit(hA.x, Ahi, Alo, 0);
            gsplit(hA.y, Ahi, Alo, 1);
            gsplit(hA.z, Ahi, Alo, 2);
            gsplit(hA.w, Ahi, Alo, 3);
            gsplit(hB.x, Ahi, Alo, 4);
            gsplit(hB.y, Ahi, Alo, 5);
            gsplit(hB.z, Ahi, Alo, 6);
            gsplit(hB.w, Ahi, Alo, 7);
            cA = __builtin_amdgcn_mfma_f32_32x32x16_bf16(Ahi, frag[2 * kk],         cA, 0, 0, 0);
            cB = __builtin_amdgcn_mfma_f32_32x32x16_bf16(Ahi, frag[8 + 2 * kk],     cB, 0, 0, 0);
            cA = __builtin_amdgcn_mfma_f32_32x32x16_bf16(Alo, frag[2 * kk],         cA, 0, 0, 0);
            cB = __builtin_amdgcn_mfma_f32_32x32x16_bf16(Alo, frag[8 + 2 * kk],     cB, 0, 0, 0);
            cA = __builtin_amdgcn_mfma_f32_32x32x16_bf16(Ahi, frag[2 * kk + 1],     cA, 0, 0, 0);
            cB = __builtin_amdgcn_mfma_f32_32x32x16_bf16(Ahi, frag[8 + 2 * kk + 1], cB, 0, 0, 0);
        }

        // ---- zero HB[next] (readers of HB[next] finished before B0 of this
        //      sub; next sub's atomics to it are ordered by the next B0)
        if (sub != 11) {
            for (int i = t; i < HBSZ; i += NTH) lds[hbn + i] = 0.0f;
        }

        // ---- refill frag with U for next substep's GEMM1 (hidden under
        //      epilogue VALU + vf_stores + B0 wait)
        if (sub != 11) {
            asm volatile("" : "+s"(uop));
            const short8* up = (const short8*)uop;
            #pragma unroll
            for (int i = 0; i < 16; ++i)
                frag[i] = up[(ub + i) * 64 + lane];
        }

        // ---- epilogue: v += ddt*(f - christ); x = wrap(x + xc*v) (+ fused c1)
        #pragma unroll
        for (int nt = 0; nt < 2; ++nt) {
            #pragma unroll
            for (int r = 0; r < 16; ++r) {
                int m = (r & 3) + 8 * (r >> 2) + 4 * rhalf;
                float fv = lds[FB + m * 516 + cg[nt]];
                float christ = (nt == 0) ? cA[r] : cB[r];
                float vn = vst[nt][r] + ddt * (fv - christ);
                vst[nt][r] = vn;
                float xn = wrap_torus(xst[nt][r] + xc * vn);
                if (dbl) xn = wrap_torus(xn + c1dt * vn);
                xst[nt][r] = xn;
            }
        }

        // ---- write new v splits for next substep
        if (sub != 11) {
            #pragma unroll
            for (int nt = 0; nt < 2; ++nt) {
                #pragma unroll
                for (int r = 0; r < 16; ++r) {
                    int m = (r & 3) + 8 * (r >> 2) + 4 * rhalf;
                    vf_store(ldsu, m, cg[nt], pack_split(vst[nt][r]));
                }
            }
        }
    }

    // ---- store outputs
    #pragma unroll
    for (int nt = 0; nt < 2; ++nt) {
        #pragma unroll
        for (int r = 0; r < 16; ++r) {
            int rrow = (r & 3) + 8 * (r >> 2) + 4 * rhalf;
            size_t idx = (size_t)(R0 + rrow) * 512 + cg[nt];
            xout[idx] = xst[nt][r];
            vout[idx] = vst[nt][r];
        }
    }
}

extern "C" void kernel_launch(void* const* d_in, const int* in_sizes, int n_in,
                              void* d_out, int out_size, void* d_ws, size_t ws_size,
                              hipStream_t stream) {
    const float* x = (const float*)d_in[0];
    const float* v = (const float*)d_in[1];
    const float* f = (const float*)d_in[2];
    const float* U = (const float*)d_in[3];
    const float* W = (const float*)d_in[4];

    float* xout = (float*)d_out;
    float* vout = xout + (size_t)32768 * 512;

    unsigned short* usw = (unsigned short*)d_ws;               // 128 KiB
    unsigned short* wsw = usw + 65536;                          // 128 KiB

    fr_prep<<<32, 256, 0, stream>>>(U, W, usw, wsw);

    hipFuncSetAttribute(reinterpret_cast<const void*>(fr_mfma),
                        hipFuncAttributeMaxDynamicSharedMemorySize, LDS_BYTES);
    fr_mfma<<<1024, NTH, LDS_BYTES, stream>>>(
        x, v, f, (const short8*)usw, (const short8*)wsw, xout, vout);
}